// Round 1
// baseline (147240.527 us; speedup 1.0000x reference)
//
#include <hip/hip_runtime.h>
#include <hip/hip_cooperative_groups.h>
#include <math.h>

namespace cg = cooperative_groups;

#define BDIM 128
#define TDIM 512
#define BT (BDIM*TDIM)

// ---------------------------------------------------------------------------
// Activation helpers (match jax.nn semantics)
// ---------------------------------------------------------------------------
__device__ __forceinline__ float eluf(float v){ return v > 0.f ? v : expm1f(v); }
__device__ __forceinline__ float softplusf(float v){ return fmaxf(v,0.f) + log1pf(expf(-fabsf(v))); }
__device__ __forceinline__ float sigmoidf(float v){ return 1.f/(1.f+expf(-v)); }

// ---------------------------------------------------------------------------
// Generic tiled GEMM (unchanged from prior session) for the hoisted big GEMMs
// ---------------------------------------------------------------------------
struct GemmP {
  const float* x1; long ldx1;
  const float* x2; long ldx2;
  int split;
  const float* w; int ldw;
  const float* biask;
  const float* bias;
  float* out;  long ldo;
  float* out2;
  int M, N, K, k0;
};

enum { SRC_CONCAT=0, SRC_ELUSUM=1 };
enum { EPI_ELU=0, EPI_PLAIN=1, EPI_PARTIAL=2, EPI_PSCALE=3 };

template<int SRC, int EPI, int BM>
__global__ __launch_bounds__(256) void gemm_k(GemmP pa, GemmP pb)
{
  const GemmP p = (blockIdx.z==0) ? pa : pb;
  constexpr int TM = BM/16;
  __shared__ float  Xs[BM][16];
  __shared__ float4 Ws4[16][16];
  const int tid = threadIdx.x;
  const int nt = tid & 15;
  const int mt = tid >> 4;
  const int n0 = blockIdx.x * 64;
  const int m0 = blockIdx.y * BM;

  float acc[TM][4];
  #pragma unroll
  for (int i=0;i<TM;i++){ acc[i][0]=0.f; acc[i][1]=0.f; acc[i][2]=0.f; acc[i][3]=0.f; }

  const int ktiles = p.K / 16;
  for (int kt=0; kt<ktiles; ++kt){
    const int kbase = p.k0 + kt*16;
    {
      const int nload4 = BM*16/4;
      if (tid < nload4){
        const int mi = tid >> 2;
        const int kk = (tid & 3) * 4;
        const int kabs = kbase + kk;
        float4 v;
        if (SRC == SRC_CONCAT){
          const float* src; long row; int k2;
          if (kabs < p.split){ src = p.x1; row = (long)(m0+mi)*p.ldx1; k2 = kabs; }
          else               { src = p.x2; row = (long)(m0+mi)*p.ldx2; k2 = kabs - p.split; }
          if (src) v = *(const float4*)(src + row + k2);
          else { v.x=0.f; v.y=0.f; v.z=0.f; v.w=0.f; }
        } else {
          const long row = (long)(m0+mi)*p.ldx1;
          float4 a = *(const float4*)(p.x1 + row + kabs);
          float4 b = *(const float4*)(p.x2 + row + kabs);
          v.x = eluf(a.x + b.x + p.biask[kabs+0]);
          v.y = eluf(a.y + b.y + p.biask[kabs+1]);
          v.z = eluf(a.z + b.z + p.biask[kabs+2]);
          v.w = eluf(a.w + b.w + p.biask[kabs+3]);
        }
        *(float4*)(&Xs[mi][kk]) = v;
      }
    }
    {
      const int kk = tid >> 4;
      const int n4 = (tid & 15) * 4;
      const int n = n0 + n4;
      const long base = (long)(kbase + kk) * p.ldw + n;
      float4 v;
      if (n + 3 < p.N) v = *(const float4*)(p.w + base);
      else {
        v.x = (n+0 < p.N) ? p.w[base+0] : 0.f;
        v.y = (n+1 < p.N) ? p.w[base+1] : 0.f;
        v.z = (n+2 < p.N) ? p.w[base+2] : 0.f;
        v.w = (n+3 < p.N) ? p.w[base+3] : 0.f;
      }
      Ws4[kk][tid & 15] = v;
    }
    __syncthreads();
    #pragma unroll
    for (int kk=0; kk<16; ++kk){
      const float4 w4 = Ws4[kk][nt];
      #pragma unroll
      for (int i=0;i<TM;i++){
        const float xv = Xs[mt*TM+i][kk];
        acc[i][0] = fmaf(xv, w4.x, acc[i][0]);
        acc[i][1] = fmaf(xv, w4.y, acc[i][1]);
        acc[i][2] = fmaf(xv, w4.z, acc[i][2]);
        acc[i][3] = fmaf(xv, w4.w, acc[i][3]);
      }
    }
    __syncthreads();
  }
  #pragma unroll
  for (int i=0;i<TM;i++){
    const int m = m0 + mt*TM + i;
    #pragma unroll
    for (int j=0;j<4;j++){
      const int n = n0 + nt*4 + j;
      if (n >= p.N) continue;
      float v = acc[i][j];
      if (EPI == EPI_PARTIAL){
        p.out[(long)m*p.ldo + n] = v;
      } else if (EPI == EPI_ELU){
        p.out[(long)m*p.ldo + n] = eluf(v + p.bias[n]);
      } else if (EPI == EPI_PLAIN){
        p.out[(long)m*p.ldo + n] = v + p.bias[n];
      } else {
        v += p.bias[n];
        if (n < 64) p.out [(long)m*64 + n]      = v;
        else        p.out2[(long)m*64 + (n-64)] = softplusf(v) + 0.1f;
      }
    }
  }
}

// ---------------------------------------------------------------------------
// Weight transpose: dst[C][R] <- src[R][C]
// ---------------------------------------------------------------------------
__global__ void transpose_k(const float* __restrict__ src, float* __restrict__ dst, int R, int C){
  __shared__ float tile[32][33];
  const int c0 = blockIdx.x*32, r0 = blockIdx.y*32;
  const int tx = threadIdx.x, ty = threadIdx.y;
  for (int i=ty; i<32; i+=8){
    const int r = r0+i, c = c0+tx;
    tile[i][tx] = (r<R && c<C) ? src[(long)r*C + c] : 0.f;
  }
  __syncthreads();
  for (int i=ty; i<32; i+=8){
    const int r = r0+tx, c = c0+i;
    if (r<R && c<C) dst[(long)c*R + r] = tile[tx][i];
  }
}

// ---------------------------------------------------------------------------
// GRU weight transpose + column permute:
// dst[k][n'] with n' = g*24 + m*8 + j  <->  original col n = m*512 + g*8 + j
// so each scan WG (col-group g) reads a contiguous 24-col slice holding the
// {r,z,a} gate columns it needs for its 8 output columns.
// ---------------------------------------------------------------------------
__global__ void gru_perm_k(const float* __restrict__ wi, const float* __restrict__ wh,
                           float* __restrict__ wiP, float* __restrict__ whP){
  const int idx = blockIdx.x*blockDim.x + threadIdx.x;
  if (idx >= 512*1536) return;
  const int k = idx / 1536, np = idx - k*1536;
  const int g = np / 24, r = np - g*24;
  const int m = r >> 3, j = r & 7;
  const long src = (long)(m*512 + g*8 + j)*512 + k;
  wiP[idx] = wi[src];
  whP[idx] = wh[src];
}

// ---------------------------------------------------------------------------
// Persistent cooperative scan kernel: the whole T=512 recurrence in one launch.
// Grid = 256 WGs x 256 threads (1 WG/CU). 4 grid syncs per timestep.
// Phases:
//   A : x = elu([stoch_{t-1}, act_t] @ priW + pri_b)           [128,512] K=80
//   BC: gi/gh dual GEMM (K=512) + GRU gates -> det_t           [128,512]
//   D : qx = elu([det_t, emb_t] @ posW + pos_b)                [128,512] K=1024
//   E : q = qx @ pdW + pd_b; q_sh/q_sc/stoch epilogue          [128,128] K=512
// ---------------------------------------------------------------------------
struct ScanP {
  const float* act;        // [B,T,16]
  const float* eps;        // [B,T,64]
  const float* emb;        // [B*T,512]
  const float* priW;       // [80][512]
  const float* pri_b;      // [512]
  const float* wiP;        // [512][1536] permuted
  const float* whP;        // [512][1536] permuted
  const float* gbi;        // [1536]
  const float* gbh;        // [1536]
  const float* posW;       // [1024][512]
  const float* pos_b;      // [512]
  const float* pdW;        // [512][128]
  const float* pd_b;       // [128]
  float* x_ws;             // [128,512]
  float* qx_ws;            // [128,512]
  float* o_stoch;          // [B,T,64]
  float* o_det;            // [B,T,512]
  float* o_qsh;            // [B,T,64]
  float* o_qsc;            // [B,T,64]
};

__global__ __launch_bounds__(256) void scan_k(ScanP p)
{
  cg::grid_group grid = cg::this_grid();
  const int wg  = blockIdx.x;
  const int tid = threadIdx.x;
  const int b8  = tid >> 3;   // 0..31 (output row within tile)
  const int j8  = tid & 7;    // 0..7  (output col within tile)

  __shared__ union {
    struct { float X[32][84]; float W[8][84]; } a;                       // 13.4 KB
    struct { float X[32][33]; float D[32][33]; float4 Wi[32][8]; float4 Wh[32][8]; } bc; // 16.6 KB
    struct { float X[32][36]; float W[8][36]; } d;                       // 5.8 KB
    struct { float X[32][36]; float W[16][36]; } e;                      // 6.9 KB
  } sm;

  for (int t = 0; t < TDIM; ++t){
    // ================= phase A: x = elu([stoch_prev, act_t] @ priW + b) ====
    {
      const int r0 = (wg >> 6) * 32;
      const int c0 = (wg & 63) * 8;
      for (int i = tid; i < 32*80; i += 256){
        const int b = i / 80, k = i - b*80;
        float v;
        if (k < 64) v = t ? p.o_stoch[((long)(r0+b)*TDIM + (t-1))*64 + k] : 0.f;
        else        v = p.act[((long)(r0+b)*TDIM + t)*16 + (k-64)];
        sm.a.X[b][k] = v;
      }
      for (int i = tid; i < 8*80; i += 256){
        const int k = i >> 3, j = i & 7;
        sm.a.W[j][k] = p.priW[(long)k*512 + c0 + j];
      }
      __syncthreads();
      float acc = 0.f;
      #pragma unroll
      for (int k4 = 0; k4 < 20; ++k4){
        const float4 x4 = *(const float4*)&sm.a.X[b8][k4*4];
        const float4 w4 = *(const float4*)&sm.a.W[j8][k4*4];
        acc = fmaf(x4.x,w4.x,acc); acc = fmaf(x4.y,w4.y,acc);
        acc = fmaf(x4.z,w4.z,acc); acc = fmaf(x4.w,w4.w,acc);
      }
      p.x_ws[(long)(r0+b8)*512 + c0 + j8] = eluf(acc + p.pri_b[c0 + j8]);
    }
    grid.sync();

    // ========= phase BC: gi/gh dual GEMM (K=512) + gates -> det_t ==========
    {
      const int r0 = (wg >> 6) * 32;
      const int g  = wg & 63;
      const float* detp = t ? (p.o_det + (long)(t-1)*512) : nullptr; // row stride T*512
      float ai0=0.f, ai1=0.f, ai2=0.f, ah0=0.f, ah1=0.f, ah2=0.f;
      for (int kt = 0; kt < 16; ++kt){
        const int kb = kt*32;
        for (int i = tid; i < 1024; i += 256){
          const int b = i >> 5, kk = i & 31;
          sm.bc.X[b][kk] = p.x_ws[(long)(r0+b)*512 + kb + kk];
          sm.bc.D[b][kk] = detp ? detp[(long)(r0+b)*TDIM*512 + kb + kk] : 0.f;
        }
        for (int i = tid; i < 768; i += 256){
          const int kk = i / 24, r = i - kk*24;
          const int m = r >> 3, j = r & 7;
          const long src = (long)(kb + kk)*1536 + g*24 + r;
          ((float*)&sm.bc.Wi[kk][j])[m] = p.wiP[src];
          ((float*)&sm.bc.Wh[kk][j])[m] = p.whP[src];
        }
        __syncthreads();
        #pragma unroll
        for (int kk = 0; kk < 32; ++kk){
          const float xv = sm.bc.X[b8][kk];
          const float dv = sm.bc.D[b8][kk];
          const float4 wi = sm.bc.Wi[kk][j8];
          const float4 wh = sm.bc.Wh[kk][j8];
          ai0 = fmaf(xv, wi.x, ai0); ai1 = fmaf(xv, wi.y, ai1); ai2 = fmaf(xv, wi.z, ai2);
          ah0 = fmaf(dv, wh.x, ah0); ah1 = fmaf(dv, wh.y, ah1); ah2 = fmaf(dv, wh.z, ah2);
        }
        __syncthreads();
      }
      const int c = g*8 + j8;
      const float ir = ai0 + p.gbi[c],        hr = ah0 + p.gbh[c];
      const float iz = ai1 + p.gbi[512 + c],  hz = ah1 + p.gbh[512 + c];
      const float ia = ai2 + p.gbi[1024 + c], ha = ah2 + p.gbh[1024 + c];
      const float r  = sigmoidf(ir + hr);
      const float z  = sigmoidf(iz + hz);
      const float nn = tanhf(ia + r*ha);
      const float dp = detp ? detp[(long)(r0+b8)*TDIM*512 + c] : 0.f;
      p.o_det[((long)(r0+b8)*TDIM + t)*512 + c] = (1.f - z)*nn + z*dp;
    }
    grid.sync();

    // ========= phase D: qx = elu([det_t, emb_t] @ posW + b)  K=1024 ========
    {
      const int r0 = (wg >> 6) * 32;
      const int c0 = (wg & 63) * 8;
      const float* detT = p.o_det + (long)t*512;   // row stride T*512
      const float* embT = p.emb   + (long)t*512;   // row stride T*512
      float acc = 0.f;
      for (int kt = 0; kt < 32; ++kt){
        const int kb = kt*32;
        for (int i = tid; i < 1024; i += 256){
          const int b = i >> 5, kk = i & 31;
          const int k = kb + kk;
          sm.d.X[b][kk] = (k < 512) ? detT[(long)(r0+b)*TDIM*512 + k]
                                    : embT[(long)(r0+b)*TDIM*512 + (k-512)];
        }
        {
          const int kk = tid >> 3, j = tid & 7;
          sm.d.W[j][kk] = p.posW[(long)(kb+kk)*512 + c0 + j];
        }
        __syncthreads();
        #pragma unroll
        for (int k4 = 0; k4 < 8; ++k4){
          const float4 x4 = *(const float4*)&sm.d.X[b8][k4*4];
          const float4 w4 = *(const float4*)&sm.d.W[j8][k4*4];
          acc = fmaf(x4.x,w4.x,acc); acc = fmaf(x4.y,w4.y,acc);
          acc = fmaf(x4.z,w4.z,acc); acc = fmaf(x4.w,w4.w,acc);
        }
        __syncthreads();
      }
      p.qx_ws[(long)(r0+b8)*512 + c0 + j8] = eluf(acc + p.pos_b[c0 + j8]);
    }
    grid.sync();

    // ========= phase E: q = qx @ pdW + b; shift/scale/stoch epilogue =======
    if (wg < 32){
      const int r0 = (wg >> 3) * 32;
      const int c0 = (wg & 7) * 8;
      float a0 = 0.f, a1 = 0.f;
      for (int kt = 0; kt < 16; ++kt){
        const int kb = kt*32;
        for (int i = tid; i < 1024; i += 256){
          const int b = i >> 5, kk = i & 31;
          sm.e.X[b][kk] = p.qx_ws[(long)(r0+b)*512 + kb + kk];
        }
        for (int i = tid; i < 512; i += 256){
          const int kk = i >> 4, jj = i & 15;
          const int c = (jj < 8) ? (c0 + jj) : (64 + c0 + (jj - 8));
          sm.e.W[jj][kk] = p.pdW[(long)(kb+kk)*128 + c];
        }
        __syncthreads();
        #pragma unroll
        for (int k4 = 0; k4 < 8; ++k4){
          const float4 x4 = *(const float4*)&sm.e.X[b8][k4*4];
          const float4 w0 = *(const float4*)&sm.e.W[j8][k4*4];
          const float4 w1 = *(const float4*)&sm.e.W[8 + j8][k4*4];
          a0 = fmaf(x4.x,w0.x,a0); a0 = fmaf(x4.y,w0.y,a0);
          a0 = fmaf(x4.z,w0.z,a0); a0 = fmaf(x4.w,w0.w,a0);
          a1 = fmaf(x4.x,w1.x,a1); a1 = fmaf(x4.y,w1.y,a1);
          a1 = fmaf(x4.z,w1.z,a1); a1 = fmaf(x4.w,w1.w,a1);
        }
        __syncthreads();
      }
      const int c = c0 + j8;
      const float v0 = a0 + p.pd_b[c];
      const float v1 = a1 + p.pd_b[64 + c];
      const float sc = softplusf(v1) + 0.1f;
      const long o = ((long)(r0+b8)*TDIM + t)*64 + c;
      const float e = p.eps[o];
      p.o_qsh[o]   = v0;
      p.o_qsc[o]   = sc;
      p.o_stoch[o] = v0 + sc*e;
    }
    grid.sync();
  }
}

// ---------------------------------------------------------------------------
extern "C" void kernel_launch(void* const* d_in, const int* in_sizes, int n_in,
                              void* d_out, int out_size, void* d_ws, size_t ws_size,
                              hipStream_t stream)
{
  const float* obs       = (const float*)d_in[0];
  const float* act       = (const float*)d_in[1];
  const float* eps       = (const float*)d_in[2];
  const float* enc_w     = (const float*)d_in[3];
  const float* enc_b     = (const float*)d_in[4];
  const float* dec_w     = (const float*)d_in[5];
  const float* dec_b     = (const float*)d_in[6];
  const float* pri_enc_w = (const float*)d_in[7];
  const float* pri_enc_b = (const float*)d_in[8];
  const float* gru_wi    = (const float*)d_in[9];
  const float* gru_bi    = (const float*)d_in[10];
  const float* gru_wh    = (const float*)d_in[11];
  const float* gru_bh    = (const float*)d_in[12];
  const float* pri_d1_w  = (const float*)d_in[13];
  const float* pri_d1_b  = (const float*)d_in[14];
  const float* pri_d2_w  = (const float*)d_in[15];
  const float* pri_d2_b  = (const float*)d_in[16];
  const float* pos_enc_w = (const float*)d_in[17];
  const float* pos_enc_b = (const float*)d_in[18];
  const float* pos_dec_w = (const float*)d_in[19];
  const float* pos_dec_b = (const float*)d_in[20];

  // ---- output sections (stochs, dets, outs, q_sh, q_sc, p_sh, p_sc)
  float* out     = (float*)d_out;
  float* o_stoch = out;
  float* o_det   = o_stoch + (long)BT*64;
  float* o_outs  = o_det   + (long)BT*512;
  float* o_qsh   = o_outs  + (long)BT*66;
  float* o_qsc   = o_qsh   + (long)BT*64;
  float* o_psh   = o_qsc   + (long)BT*64;
  float* o_psc   = o_psh   + (long)BT*64;

  // ---- workspace carve-up
  float* w = (float*)d_ws;
  float* enc_wT     = w; w += 64*512;
  float* pri_enc_wT = w; w += 80*512;
  float* gru_wiP    = w; w += 512*1536;
  float* gru_whP    = w; w += 512*1536;
  float* pri_d1T    = w; w += 512*512;
  float* pri_d2T    = w; w += 512*128;
  float* pos_encT   = w; w += 1024*512;
  float* pos_decT   = w; w += 512*128;
  float* dec_wT     = w; w += 576*66;
  float* emb        = w; w += (long)BT*512;   // reused as px after the scan
  float* x_ws       = w; w += 128*512;
  float* qx_ws      = w; w += 128*512;

  // ---- pre-pass: transpose weights to [K][N]
  {
    struct { const float* s; float* d; int R, C; } tps[7] = {
      {enc_w,     enc_wT,     512, 64  },
      {pri_enc_w, pri_enc_wT, 512, 80  },
      {pri_d1_w,  pri_d1T,    512, 512 },
      {pri_d2_w,  pri_d2T,    128, 512 },
      {pos_enc_w, pos_encT,   512, 1024},
      {pos_dec_w, pos_decT,   128, 512 },
      {dec_w,     dec_wT,     66,  576 },
    };
    for (int i=0;i<7;i++){
      dim3 g((tps[i].C+31)/32, (tps[i].R+31)/32), b(32,8);
      hipLaunchKernelGGL(transpose_k, g, b, 0, stream, tps[i].s, tps[i].d, tps[i].R, tps[i].C);
    }
    hipLaunchKernelGGL(gru_perm_k, dim3((512*1536+255)/256), dim3(256), 0, stream,
                       gru_wi, gru_wh, gru_wiP, gru_whP);
  }

  // ---- pre-pass: obs embedding  emb = elu(obs @ enc_w^T + enc_b)
  {
    GemmP p{}; p.x1=obs; p.ldx1=64; p.split=64; p.w=enc_wT; p.ldw=512;
    p.bias=enc_b; p.out=emb; p.ldo=512; p.M=BT; p.N=512; p.K=64; p.k0=0;
    hipLaunchKernelGGL((gemm_k<SRC_CONCAT,EPI_ELU,64>), dim3(8,BT/64,1), dim3(256), 0, stream, p, p);
  }

  // ---- the whole scan in ONE persistent cooperative kernel
  {
    ScanP p;
    p.act = act; p.eps = eps; p.emb = emb;
    p.priW = pri_enc_wT; p.pri_b = pri_enc_b;
    p.wiP = gru_wiP; p.whP = gru_whP; p.gbi = gru_bi; p.gbh = gru_bh;
    p.posW = pos_encT; p.pos_b = pos_enc_b;
    p.pdW = pos_decT;  p.pd_b = pos_dec_b;
    p.x_ws = x_ws; p.qx_ws = qx_ws;
    p.o_stoch = o_stoch; p.o_det = o_det; p.o_qsh = o_qsh; p.o_qsc = o_qsc;
    void* args[] = { &p };
    hipLaunchCooperativeKernel((const void*)scan_k, dim3(256), dim3(256), args, 0, stream);
  }

  // ---- prior decode, hoisted out of the scan (parallel over all B*T)
  {
    GemmP p{}; p.x1 = o_det; p.ldx1 = 512; p.split = 512;
    p.w = pri_d1T; p.ldw = 512; p.bias = pri_d1_b;
    p.out = emb /* reuse as px */; p.ldo = 512; p.M = BT; p.N = 512; p.K = 512; p.k0 = 0;
    hipLaunchKernelGGL((gemm_k<SRC_CONCAT,EPI_ELU,64>), dim3(8,BT/64,1), dim3(256), 0, stream, p, p);
  }
  {
    GemmP p{}; p.x1 = emb; p.ldx1 = 512; p.split = 512;
    p.w = pri_d2T; p.ldw = 128; p.bias = pri_d2_b;
    p.out = o_psh; p.out2 = o_psc; p.M = BT; p.N = 128; p.K = 512; p.k0 = 0;
    hipLaunchKernelGGL((gemm_k<SRC_CONCAT,EPI_PSCALE,64>), dim3(2,BT/64,1), dim3(256), 0, stream, p, p);
  }
  // ---- final decoder: outs = [stoch, det] @ dec_w^T + dec_b   (N=66)
  {
    GemmP p{}; p.x1 = o_stoch; p.ldx1 = 64; p.x2 = o_det; p.ldx2 = 512; p.split = 64;
    p.w = dec_wT; p.ldw = 66; p.bias = dec_b;
    p.out = o_outs; p.ldo = 66; p.M = BT; p.N = 66; p.K = 576; p.k0 = 0;
    hipLaunchKernelGGL((gemm_k<SRC_CONCAT,EPI_PLAIN,64>), dim3(2,BT/64,1), dim3(256), 0, stream, p, p);
  }
}

// Round 2
// 68138.330 us; speedup vs baseline: 2.1609x; 2.1609x over previous
//
#include <hip/hip_runtime.h>
#include <math.h>

#define BDIM 128
#define TDIM 512
#define BT (BDIM*TDIM)

// ---------------------------------------------------------------------------
// Activation helpers (match jax.nn semantics)
// ---------------------------------------------------------------------------
__device__ __forceinline__ float eluf(float v){ return v > 0.f ? v : expm1f(v); }
__device__ __forceinline__ float softplusf(float v){ return fmaxf(v,0.f) + log1pf(expf(-fabsf(v))); }
__device__ __forceinline__ float sigmoidf(float v){ return 1.f/(1.f+expf(-v)); }

// ---------------------------------------------------------------------------
// Generic tiled GEMM:  C[M,N] = epi( X[M,K] @ W_T[K,N] + bias )
// SRC_CONCAT : X from 2-way concat (x1 k<split, x2 after; null -> zeros)
// SRC_ELUSUM : X = elu(x1 + x2 + biask)
// SRC_GATE   : X = GRU gate output computed inline from gi(x1)/gh(x2)/det_prev(x3)
//              for kabs<split; else X = x1[kabs-512] (emb half, use split=0).
//              blockIdx.x==0 blocks also materialize det into p.out2
//              (row stride TDIM*512).
// ---------------------------------------------------------------------------
struct GemmP {
  const float* x1; long ldx1;
  const float* x2; long ldx2;
  const float* x3;        // det_prev for SRC_GATE (row stride TDIM*512)
  int split;
  const float* w; int ldw;
  const float* biask;     // k-dim bias for ELUSUM source
  const float* bias;      // n-dim output bias
  float* out;  long ldo;
  float* out2;            // PSCALE second output / GATE det materialization
  int M, N, K, k0;
};

enum { SRC_CONCAT=0, SRC_ELUSUM=1, SRC_GATE=2 };
enum { EPI_ELU=0, EPI_PLAIN=1, EPI_PARTIAL=2, EPI_PSCALE=3 };

template<int SRC, int EPI, int BM>
__global__ __launch_bounds__(256) void gemm_k(GemmP pa, GemmP pb)
{
  const GemmP p = (blockIdx.z==0) ? pa : pb;
  constexpr int TM = BM/16;
  __shared__ float  Xs[BM][16];
  __shared__ float4 Ws4[16][16];
  const int tid = threadIdx.x;
  const int nt = tid & 15;
  const int mt = tid >> 4;
  const int n0 = blockIdx.x * 64;
  const int m0 = blockIdx.y * BM;

  float acc[TM][4];
  #pragma unroll
  for (int i=0;i<TM;i++){ acc[i][0]=0.f; acc[i][1]=0.f; acc[i][2]=0.f; acc[i][3]=0.f; }

  const int ktiles = p.K / 16;
  for (int kt=0; kt<ktiles; ++kt){
    const int kbase = p.k0 + kt*16;
    // ---- X tile
    if (SRC == SRC_GATE){
      // one element per thread (BM must be 16)
      const int mi = tid >> 4;
      const int kk = tid & 15;
      const int kabs = kbase + kk;
      float xv;
      if (kabs < p.split){
        const long g = (long)(m0+mi)*p.ldx1 + kabs;   // ldx1 = 1536
        const float ir = p.x1[g], iz = p.x1[g+512], ia = p.x1[g+1024];
        const float hr = p.x2[g], hz = p.x2[g+512], ha = p.x2[g+1024];
        const float dp = p.x3 ? p.x3[(long)(m0+mi)*TDIM*512 + kabs] : 0.f;
        const float r  = sigmoidf(ir+hr);
        const float z  = sigmoidf(iz+hz);
        const float nn = tanhf(ia + r*ha);
        xv = (1.f - z)*nn + z*dp;
        if (blockIdx.x==0 && p.out2)
          p.out2[(long)(m0+mi)*TDIM*512 + kabs] = xv;
      } else {
        // emb half: x1 = emb + t*512, row stride ldx1 ... but gate z0 never
        // reaches here (split=512); z1 uses split=0 so always this path.
        xv = p.x1[(long)(m0+mi)*p.ldx1 + (kabs - 512)];
      }
      Xs[mi][kk] = xv;
    } else {
      const int nload4 = BM*16/4;
      if (tid < nload4){
        const int mi = tid >> 2;
        const int kk = (tid & 3) * 4;
        const int kabs = kbase + kk;
        float4 v;
        if (SRC == SRC_CONCAT){
          const float* src; long row; int k2;
          if (kabs < p.split){ src = p.x1; row = (long)(m0+mi)*p.ldx1; k2 = kabs; }
          else               { src = p.x2; row = (long)(m0+mi)*p.ldx2; k2 = kabs - p.split; }
          if (src) v = *(const float4*)(src + row + k2);
          else { v.x=0.f; v.y=0.f; v.z=0.f; v.w=0.f; }
        } else { // SRC_ELUSUM
          const long row = (long)(m0+mi)*p.ldx1;
          float4 a = *(const float4*)(p.x1 + row + kabs);
          float4 b = *(const float4*)(p.x2 + row + kabs);
          v.x = eluf(a.x + b.x + p.biask[kabs+0]);
          v.y = eluf(a.y + b.y + p.biask[kabs+1]);
          v.z = eluf(a.z + b.z + p.biask[kabs+2]);
          v.w = eluf(a.w + b.w + p.biask[kabs+3]);
        }
        *(float4*)(&Xs[mi][kk]) = v;
      }
    }
    // ---- W tile: 16 x 64 from transposed [K][N]
    {
      const int kk = tid >> 4;
      const int n4 = (tid & 15) * 4;
      const int n = n0 + n4;
      const long base = (long)(kbase + kk) * p.ldw + n;
      float4 v;
      if (n + 3 < p.N) v = *(const float4*)(p.w + base);
      else {
        v.x = (n+0 < p.N) ? p.w[base+0] : 0.f;
        v.y = (n+1 < p.N) ? p.w[base+1] : 0.f;
        v.z = (n+2 < p.N) ? p.w[base+2] : 0.f;
        v.w = (n+3 < p.N) ? p.w[base+3] : 0.f;
      }
      Ws4[kk][tid & 15] = v;
    }
    __syncthreads();
    #pragma unroll
    for (int kk=0; kk<16; ++kk){
      const float4 w4 = Ws4[kk][nt];
      #pragma unroll
      for (int i=0;i<TM;i++){
        const float xv = Xs[mt*TM+i][kk];
        acc[i][0] = fmaf(xv, w4.x, acc[i][0]);
        acc[i][1] = fmaf(xv, w4.y, acc[i][1]);
        acc[i][2] = fmaf(xv, w4.z, acc[i][2]);
        acc[i][3] = fmaf(xv, w4.w, acc[i][3]);
      }
    }
    __syncthreads();
  }
  // ---- epilogue
  #pragma unroll
  for (int i=0;i<TM;i++){
    const int m = m0 + mt*TM + i;
    #pragma unroll
    for (int j=0;j<4;j++){
      const int n = n0 + nt*4 + j;
      if (n >= p.N) continue;
      float v = acc[i][j];
      if (EPI == EPI_PARTIAL){
        p.out[(long)m*p.ldo + n] = v;
      } else if (EPI == EPI_ELU){
        p.out[(long)m*p.ldo + n] = eluf(v + p.bias[n]);
      } else if (EPI == EPI_PLAIN){
        p.out[(long)m*p.ldo + n] = v + p.bias[n];
      } else { // EPI_PSCALE
        v += p.bias[n];
        if (n < 64) p.out [(long)m*64 + n]      = v;
        else        p.out2[(long)m*64 + (n-64)] = softplusf(v) + 0.1f;
      }
    }
  }
}

// ---------------------------------------------------------------------------
// Weight transpose: dst[C][R] <- src[R][C]
// ---------------------------------------------------------------------------
__global__ void transpose_k(const float* __restrict__ src, float* __restrict__ dst, int R, int C){
  __shared__ float tile[32][33];
  const int c0 = blockIdx.x*32, r0 = blockIdx.y*32;
  const int tx = threadIdx.x, ty = threadIdx.y; // 32 x 8
  for (int i=ty; i<32; i+=8){
    const int r = r0+i, c = c0+tx;
    tile[i][tx] = (r<R && c<C) ? src[(long)r*C + c] : 0.f;
  }
  __syncthreads();
  for (int i=ty; i<32; i+=8){
    const int r = r0+tx, c = c0+i;
    if (r<R && c<C) dst[(long)c*R + r] = tile[tx][i];
  }
}

// ---------------------------------------------------------------------------
// Fused E kernel: posterior head GEMM (K=512, ELUSUM source) + softplus/stoch
// epilogue + NEXT step's phase A (x_{t+1} = elu([stoch_t, act_{t+1}] @ priW)).
// Grid = 16 blocks x 256 threads; each block owns 8 batch rows.
// ---------------------------------------------------------------------------
struct EP {
  const float* qx1a;      // [128,512] partial (K 0..511 of pos_enc)
  const float* qx1b;      // [128,512] partial (K 512..1023)
  const float* biask;     // pos_enc_b [512]
  const float* pdW;       // pos_dec transposed [512][128]
  const float* pd_b;      // [128]
  const float* eps_t;     // eps + t*64, row stride TDIM*64
  const float* act_next;  // act + (t+1)*16, row stride TDIM*16 (null at t=T-1)
  const float* priW;      // pri_enc transposed [80][512]
  const float* pri_b;     // [512]
  float* o_qsh; float* o_qsc; float* o_stoch;  // + t*64, row stride TDIM*64
  float* x_ws;            // [128,512] -> input of next BC
};

__global__ __launch_bounds__(256) void e_k(EP p)
{
  __shared__ float  Xs[8][16];
  __shared__ float4 Ws4[16][32];
  __shared__ float  Q[8][132];
  __shared__ float  X2[8][84];
  __shared__ float4 W2[80][32];
  const int tid = threadIdx.x;
  const int r0 = blockIdx.x * 8;
  const int mt = tid >> 5;      // 0..7 : row
  const int nt = tid & 31;      // col group (4 cols)

  // ---- head GEMM: q[8][128] = elu(qx1a+qx1b+biask)[8,512] @ pdW
  float a0=0.f, a1=0.f, a2=0.f, a3=0.f;
  for (int kt=0; kt<32; ++kt){
    const int kb = kt*16;
    if (tid < 32){
      const int mi = tid >> 2, kk = (tid & 3)*4;
      const long row = (long)(r0+mi)*512 + kb + kk;
      float4 a = *(const float4*)(p.qx1a + row);
      float4 b = *(const float4*)(p.qx1b + row);
      float4 v;
      v.x = eluf(a.x + b.x + p.biask[kb+kk+0]);
      v.y = eluf(a.y + b.y + p.biask[kb+kk+1]);
      v.z = eluf(a.z + b.z + p.biask[kb+kk+2]);
      v.w = eluf(a.w + b.w + p.biask[kb+kk+3]);
      *(float4*)&Xs[mi][kk] = v;
    }
    {
      const int r = tid >> 5, c4 = tid & 31;
      Ws4[r][c4]   = *(const float4*)(p.pdW + (long)(kb+r)*128   + c4*4);
      Ws4[r+8][c4] = *(const float4*)(p.pdW + (long)(kb+r+8)*128 + c4*4);
    }
    __syncthreads();
    #pragma unroll
    for (int kk=0; kk<16; ++kk){
      const float x = Xs[mt][kk];
      const float4 w = Ws4[kk][nt];
      a0 = fmaf(x, w.x, a0); a1 = fmaf(x, w.y, a1);
      a2 = fmaf(x, w.z, a2); a3 = fmaf(x, w.w, a3);
    }
    __syncthreads();
  }
  Q[mt][nt*4+0]=a0; Q[mt][nt*4+1]=a1; Q[mt][nt*4+2]=a2; Q[mt][nt*4+3]=a3;
  __syncthreads();

  // ---- stoch epilogue: shift/scale/stoch, also stage stoch into X2
  for (int i=tid; i<8*64; i+=256){
    const int r = i>>6, c = i&63;
    const float v0 = Q[r][c]    + p.pd_b[c];
    const float v1 = Q[r][64+c] + p.pd_b[64+c];
    const float sc = softplusf(v1) + 0.1f;
    const long o = (long)(r0+r)*TDIM*64 + c;
    const float st = v0 + sc*p.eps_t[o];
    p.o_qsh[o]   = v0;
    p.o_qsc[o]   = sc;
    p.o_stoch[o] = st;
    X2[r][c] = st;
  }

  // ---- next-step phase A: x_{t+1} = elu([stoch_t, act_{t+1}] @ priW + b)
  if (p.act_next){
    for (int i=tid; i<8*16; i+=256){
      const int r = i>>4, c = i&15;
      X2[r][64+c] = p.act_next[(long)(r0+r)*TDIM*16 + c];
    }
    __syncthreads();
    for (int cc=0; cc<4; ++cc){
      const int c0 = cc*128;
      for (int i=tid; i<80*32; i+=256){
        const int k = i>>5, n4 = i&31;
        W2[k][n4] = *(const float4*)(p.priW + (long)k*512 + c0 + n4*4);
      }
      __syncthreads();
      float b0=0.f, b1=0.f, b2=0.f, b3=0.f;
      #pragma unroll
      for (int k=0; k<80; ++k){
        const float x = X2[mt][k];
        const float4 w = W2[k][nt];
        b0 = fmaf(x, w.x, b0); b1 = fmaf(x, w.y, b1);
        b2 = fmaf(x, w.z, b2); b3 = fmaf(x, w.w, b3);
      }
      const int c = c0 + nt*4;
      float* o = p.x_ws + (long)(r0+mt)*512 + c;
      o[0] = eluf(b0 + p.pri_b[c+0]);
      o[1] = eluf(b1 + p.pri_b[c+1]);
      o[2] = eluf(b2 + p.pri_b[c+2]);
      o[3] = eluf(b3 + p.pri_b[c+3]);
      __syncthreads();
    }
  }
}

// ---------------------------------------------------------------------------
extern "C" void kernel_launch(void* const* d_in, const int* in_sizes, int n_in,
                              void* d_out, int out_size, void* d_ws, size_t ws_size,
                              hipStream_t stream)
{
  const float* obs       = (const float*)d_in[0];
  const float* act       = (const float*)d_in[1];
  const float* eps       = (const float*)d_in[2];
  const float* enc_w     = (const float*)d_in[3];
  const float* enc_b     = (const float*)d_in[4];
  const float* dec_w     = (const float*)d_in[5];
  const float* dec_b     = (const float*)d_in[6];
  const float* pri_enc_w = (const float*)d_in[7];
  const float* pri_enc_b = (const float*)d_in[8];
  const float* gru_wi    = (const float*)d_in[9];
  const float* gru_bi    = (const float*)d_in[10];
  const float* gru_wh    = (const float*)d_in[11];
  const float* gru_bh    = (const float*)d_in[12];
  const float* pri_d1_w  = (const float*)d_in[13];
  const float* pri_d1_b  = (const float*)d_in[14];
  const float* pri_d2_w  = (const float*)d_in[15];
  const float* pri_d2_b  = (const float*)d_in[16];
  const float* pos_enc_w = (const float*)d_in[17];
  const float* pos_enc_b = (const float*)d_in[18];
  const float* pos_dec_w = (const float*)d_in[19];
  const float* pos_dec_b = (const float*)d_in[20];

  // ---- output sections (return order: stochs, dets, outs, q_sh, q_sc, p_sh, p_sc)
  float* out     = (float*)d_out;
  float* o_stoch = out;
  float* o_det   = o_stoch + (long)BT*64;
  float* o_outs  = o_det   + (long)BT*512;
  float* o_qsh   = o_outs  + (long)BT*66;
  float* o_qsc   = o_qsh   + (long)BT*64;
  float* o_psh   = o_qsc   + (long)BT*64;
  float* o_psc   = o_psh   + (long)BT*64;

  // ---- workspace carve-up
  float* w = (float*)d_ws;
  float* enc_wT     = w; w += 64*512;
  float* pri_enc_wT = w; w += 80*512;
  float* gru_wiT    = w; w += 512*1536;
  float* gru_whT    = w; w += 512*1536;
  float* pri_d1T    = w; w += 512*512;
  float* pri_d2T    = w; w += 512*128;
  float* pos_encT   = w; w += 1024*512;
  float* pos_decT   = w; w += 512*128;
  float* dec_wT     = w; w += 576*66;
  float* emb        = w; w += (long)BT*512;   // reused as px after the scan
  float* x_ws       = w; w += 128*512;
  float* gi_ws      = w; w += 128*1536;
  float* gh_ws      = w; w += 128*1536;
  float* qx1a       = w; w += 128*512;
  float* qx1b       = w; w += 128*512;

  // ---- pre-pass: transpose all weights to [K][N]
  {
    struct { const float* s; float* d; int R, C; } tps[9] = {
      {enc_w,     enc_wT,     512, 64  },
      {pri_enc_w, pri_enc_wT, 512, 80  },
      {gru_wi,    gru_wiT,    1536,512 },
      {gru_wh,    gru_whT,    1536,512 },
      {pri_d1_w,  pri_d1T,    512, 512 },
      {pri_d2_w,  pri_d2T,    128, 512 },
      {pos_enc_w, pos_encT,   512, 1024},
      {pos_dec_w, pos_decT,   128, 512 },
      {dec_w,     dec_wT,     66,  576 },
    };
    for (int i=0;i<9;i++){
      dim3 g((tps[i].C+31)/32, (tps[i].R+31)/32), b(32,8);
      hipLaunchKernelGGL(transpose_k, g, b, 0, stream, tps[i].s, tps[i].d, tps[i].R, tps[i].C);
    }
  }

  // ---- pre-pass: obs embedding  emb[b,t,:] = elu(obs @ enc_w^T + enc_b)
  {
    GemmP p{}; p.x1=obs; p.ldx1=64; p.split=64; p.w=enc_wT; p.ldw=512;
    p.bias=enc_b; p.out=emb; p.ldo=512; p.M=BT; p.N=512; p.K=64; p.k0=0;
    hipLaunchKernelGGL((gemm_k<SRC_CONCAT,EPI_ELU,64>), dim3(8,BT/64,1), dim3(256), 0, stream, p, p);
  }

  // ---- t=0 phase A: x_0 = elu([0, act_0] @ pri_enc_w^T + b)
  {
    GemmP p{};
    p.x1 = nullptr; p.ldx1 = (long)TDIM*64;
    p.x2 = act;     p.ldx2 = (long)TDIM*16;
    p.split = 64; p.w = pri_enc_wT; p.ldw = 512; p.bias = pri_enc_b;
    p.out = x_ws; p.ldo = 512; p.M = 128; p.N = 512; p.K = 80; p.k0 = 0;
    hipLaunchKernelGGL((gemm_k<SRC_CONCAT,EPI_ELU,16>), dim3(8,8,1), dim3(256), 0, stream, p, p);
  }

  // ---- sequential scan: 3 launches per step (BC, D, E)
  for (int t=0; t<TDIM; ++t){
    const float* det_prev = t ? (o_det + (long)(t-1)*512) : nullptr;
    // BC: gi = x @ Wi^T + bi ;  gh = det_{t-1} @ Wh^T + bh
    {
      GemmP p0{}; p0.x1 = x_ws; p0.ldx1 = 512; p0.split = 512;
      p0.w = gru_wiT; p0.ldw = 1536; p0.bias = gru_bi;
      p0.out = gi_ws; p0.ldo = 1536; p0.M = 128; p0.N = 1536; p0.K = 512; p0.k0 = 0;
      GemmP p1 = p0;
      p1.x1 = det_prev; p1.ldx1 = (long)TDIM*512;
      p1.w = gru_whT; p1.bias = gru_bh; p1.out = gh_ws;
      hipLaunchKernelGGL((gemm_k<SRC_CONCAT,EPI_PLAIN,16>), dim3(24,8,2), dim3(256), 0, stream, p0, p1);
    }
    // D: posterior hidden partials; z0 computes GRU gates inline (X = det_t)
    //    and materializes o_det[t]; z1 covers the emb K-half.
    {
      GemmP p0{};
      p0.x1 = gi_ws; p0.ldx1 = 1536;
      p0.x2 = gh_ws; p0.ldx2 = 1536;
      p0.x3 = det_prev;
      p0.split = 512;
      p0.w = pos_encT; p0.ldw = 512;
      p0.out = qx1a; p0.ldo = 512; p0.out2 = o_det + (long)t*512;
      p0.M = 128; p0.N = 512; p0.K = 512; p0.k0 = 0;
      GemmP p1{};
      p1.x1 = emb + (long)t*512; p1.ldx1 = (long)TDIM*512;
      p1.split = 0;                       // always emb path
      p1.w = pos_encT; p1.ldw = 512;
      p1.out = qx1b; p1.ldo = 512; p1.out2 = nullptr;
      p1.M = 128; p1.N = 512; p1.K = 512; p1.k0 = 512;
      hipLaunchKernelGGL((gemm_k<SRC_GATE,EPI_PARTIAL,16>), dim3(8,8,2), dim3(256), 0, stream, p0, p1);
    }
    // E: posterior head + stoch epilogue + next-step phase A
    {
      EP p;
      p.qx1a = qx1a; p.qx1b = qx1b; p.biask = pos_enc_b;
      p.pdW = pos_decT; p.pd_b = pos_dec_b;
      p.eps_t = eps + (long)t*64;
      p.act_next = (t+1 < TDIM) ? (act + (long)(t+1)*16) : nullptr;
      p.priW = pri_enc_wT; p.pri_b = pri_enc_b;
      p.o_qsh = o_qsh + (long)t*64;
      p.o_qsc = o_qsc + (long)t*64;
      p.o_stoch = o_stoch + (long)t*64;
      p.x_ws = x_ws;
      hipLaunchKernelGGL(e_k, dim3(16), dim3(256), 0, stream, p);
    }
  }

  // ---- prior decode, hoisted out of the scan (parallel over all B*T)
  {
    GemmP p{}; p.x1 = o_det; p.ldx1 = 512; p.split = 512;
    p.w = pri_d1T; p.ldw = 512; p.bias = pri_d1_b;
    p.out = emb /* reuse as px */; p.ldo = 512; p.M = BT; p.N = 512; p.K = 512; p.k0 = 0;
    hipLaunchKernelGGL((gemm_k<SRC_CONCAT,EPI_ELU,64>), dim3(8,BT/64,1), dim3(256), 0, stream, p, p);
  }
  {
    GemmP p{}; p.x1 = emb; p.ldx1 = 512; p.split = 512;
    p.w = pri_d2T; p.ldw = 128; p.bias = pri_d2_b;
    p.out = o_psh; p.out2 = o_psc; p.M = BT; p.N = 128; p.K = 512; p.k0 = 0;
    hipLaunchKernelGGL((gemm_k<SRC_CONCAT,EPI_PSCALE,64>), dim3(2,BT/64,1), dim3(256), 0, stream, p, p);
  }
  // ---- final decoder: outs = [stoch, det] @ dec_w^T + dec_b   (N=66)
  {
    GemmP p{}; p.x1 = o_stoch; p.ldx1 = 64; p.x2 = o_det; p.ldx2 = 512; p.split = 64;
    p.w = dec_wT; p.ldw = 66; p.bias = dec_b;
    p.out = o_outs; p.ldo = 66; p.M = BT; p.N = 66; p.K = 576; p.k0 = 0;
    hipLaunchKernelGGL((gemm_k<SRC_CONCAT,EPI_PLAIN,64>), dim3(2,BT/64,1), dim3(256), 0, stream, p, p);
  }
}